// Round 1
// baseline (324.485 us; speedup 1.0000x reference)
//
#include <hip/hip_runtime.h>

// Problem dims are fixed by setup_inputs(): B=8, C=64, H=256, W=256.
#define B_ 8
#define C_ 64
#define H_ 256
#define W_ 256

__global__ __launch_bounds__(256) void st_warp_kernel(
    const float* __restrict__ src,   // [B,C,H,W]
    const float* __restrict__ flow,  // [B,2,H,W]
    float* __restrict__ out)         // [B,C,H,W]
{
    const int HW = H_ * W_;

    // XCD swizzle: grid = B*H = 2048 blocks. Hardware round-robins blocks
    // across the 8 XCDs (id % 8). Remap so XCD x gets a contiguous run of
    // rows (one batch), executed in increasing h -> src row-band stays in
    // the 4 MiB per-XCD L2.
    int id    = blockIdx.x;              // 0..2047
    int xcd   = id & 7;
    int local = id >> 3;                 // 0..255
    int row   = xcd * 256 + local;       // 0..2047
    int b     = row >> 8;                // batch
    int h     = row & 255;
    int w     = threadIdx.x;             // 0..255

    // --- coords (replicate reference arithmetic incl. the identity round trip)
    const float* flow_b = flow + (size_t)b * 2 * HW;
    float fy = flow_b[h * W_ + w];
    float fx = flow_b[HW + h * W_ + w];
    float new_y = (float)h + fy;
    float new_x = (float)w + fx;
    float ny = 2.0f * (new_y / (float)(H_ - 1) - 0.5f);
    float nx = 2.0f * (new_x / (float)(W_ - 1) - 0.5f);
    float py = (ny + 1.0f) * 0.5f * (float)(H_ - 1);
    float px = (nx + 1.0f) * 0.5f * (float)(W_ - 1);

    // --- bilinear setup
    float y0f = floorf(py), x0f = floorf(px);
    int y0 = (int)y0f, x0 = (int)x0f;
    int y1 = y0 + 1,  x1 = x0 + 1;
    float wy1 = py - y0f, wy0 = 1.0f - wy1;
    float wx1 = px - x0f, wx0 = 1.0f - wx1;

    bool vy0 = (y0 >= 0) & (y0 < H_);
    bool vy1 = (y1 >= 0) & (y1 < H_);
    bool vx0 = (x0 >= 0) & (x0 < W_);
    bool vx1 = (x1 >= 0) & (x1 < W_);

    float w00 = wy0 * wx0 * (float)(vy0 & vx0);
    float w01 = wy0 * wx1 * (float)(vy0 & vx1);
    float w10 = wy1 * wx0 * (float)(vy1 & vx0);
    float w11 = wy1 * wx1 * (float)(vy1 & vx1);

    int y0c = min(max(y0, 0), H_ - 1);
    int y1c = min(max(y1, 0), H_ - 1);
    int x0c = min(max(x0, 0), W_ - 1);
    int x1c = min(max(x1, 0), W_ - 1);

    size_t base = (size_t)b * C_ * HW;
    const float* s00 = src + base + (size_t)y0c * W_ + x0c;
    const float* s01 = src + base + (size_t)y0c * W_ + x1c;
    const float* s10 = src + base + (size_t)y1c * W_ + x0c;
    const float* s11 = src + base + (size_t)y1c * W_ + x1c;
    float* ob = out + base + (size_t)h * W_ + w;

    #pragma unroll 4
    for (int c = 0; c < C_; ++c) {
        size_t off = (size_t)c * HW;
        float v = s00[off] * w00
                + s01[off] * w01
                + s10[off] * w10
                + s11[off] * w11;
        ob[off] = v;
    }
}

extern "C" void kernel_launch(void* const* d_in, const int* in_sizes, int n_in,
                              void* d_out, int out_size, void* d_ws, size_t ws_size,
                              hipStream_t stream) {
    const float* src  = (const float*)d_in[0];
    const float* flow = (const float*)d_in[1];
    float* out = (float*)d_out;
    dim3 grid(B_ * H_);
    dim3 block(W_);
    st_warp_kernel<<<grid, block, 0, stream>>>(src, flow, out);
}

// Round 2
// 281.279 us; speedup vs baseline: 1.1536x; 1.1536x over previous
//
#include <hip/hip_runtime.h>

// Problem dims fixed by setup_inputs(): B=8, C=64, H=256, W=256.
#define B_ 8
#define C_ 64
#define H_ 256
#define W_ 256

__global__ __launch_bounds__(256) void st_warp_kernel(
    const float* __restrict__ src,   // [B,C,H,W]
    const float* __restrict__ flow,  // [B,2,H,W]
    float* __restrict__ out)         // [B,C,H,W]
{
    const int HW = H_ * W_;

    // XCD swizzle: 2048 x-blocks round-robin across 8 XCDs (id % 8). Remap so
    // each XCD owns one batch, rows in increasing h -> src row band stays in
    // the 4 MiB per-XCD L2.
    int id    = blockIdx.x;              // 0..2047
    int xcd   = id & 7;
    int local = id >> 3;                 // 0..255
    int row   = xcd * 256 + local;       // 0..2047
    int b     = row >> 8;                // batch
    int h     = row & 255;
    int w     = threadIdx.x;             // 0..255
    int cbase = blockIdx.y * (C_ / 2);   // 2 blocks split the 64 channels

    // --- coords (replicate reference arithmetic incl. identity round trip)
    const float* flow_b = flow + (size_t)b * 2 * HW;
    float fy = flow_b[h * W_ + w];
    float fx = flow_b[HW + h * W_ + w];
    float new_y = (float)h + fy;
    float new_x = (float)w + fx;
    float ny = 2.0f * (new_y / (float)(H_ - 1) - 0.5f);
    float nx = 2.0f * (new_x / (float)(W_ - 1) - 0.5f);
    float py = (ny + 1.0f) * 0.5f * (float)(H_ - 1);
    float px = (nx + 1.0f) * 0.5f * (float)(W_ - 1);

    // --- bilinear setup
    float y0f = floorf(py), x0f = floorf(px);
    int y0 = (int)y0f, x0 = (int)x0f;
    int y1 = y0 + 1,  x1 = x0 + 1;
    float wy1 = py - y0f, wy0 = 1.0f - wy1;
    float wx1 = px - x0f, wx0 = 1.0f - wx1;

    bool vy0 = (y0 >= 0) & (y0 < H_);
    bool vy1 = (y1 >= 0) & (y1 < H_);
    bool vx0 = (x0 >= 0) & (x0 < W_);
    bool vx1 = (x1 >= 0) & (x1 < W_);

    float w00 = wy0 * wx0 * (float)(vy0 & vx0);
    float w01 = wy0 * wx1 * (float)(vy0 & vx1);
    float w10 = wy1 * wx0 * (float)(vy1 & vx0);
    float w11 = wy1 * wx1 * (float)(vy1 & vx1);

    int y0c = min(max(y0, 0), H_ - 1);
    int y1c = min(max(y1, 0), H_ - 1);
    int x0c = min(max(x0, 0), W_ - 1);
    int x1c = min(max(x1, 0), W_ - 1);

    // Pair the two x-samples into one float2 load per row.
    // xl = clamp(x0, 0, W-2): pair covers [xl, xl+1], always in-bounds.
    //  x0 in [0,W-2] -> x0c=xl,   x1c=xl+1
    //  x0 < 0        -> x0c=0=xl, x1c in {xl, xl+1}
    //  x0 >= W-1     -> x0c=W-1=xl+1, x1c=W-1=xl+1
    // So x0c,x1c are each always xl or xl+1; select per-thread (loop-invariant).
    int xl = min(max(x0, 0), W_ - 2);
    bool sel0 = (x0c != xl);     // v00 = sel0 ? p.y : p.x
    bool sel1 = (x1c == xl);     // v01 = sel1 ? p.x : p.y

    size_t base = (size_t)b * C_ * HW + (size_t)cbase * HW;
    const float* r0 = src + base + (size_t)y0c * W_ + xl;
    const float* r1 = src + base + (size_t)y1c * W_ + xl;
    float* ob = out + base + (size_t)h * W_ + w;

    #pragma unroll 8
    for (int c = 0; c < C_ / 2; ++c) {
        size_t off = (size_t)c * HW;
        float2 p0, p1;
        __builtin_memcpy(&p0, r0 + off, 8);
        __builtin_memcpy(&p1, r1 + off, 8);
        float v00 = sel0 ? p0.y : p0.x;
        float v01 = sel1 ? p0.x : p0.y;
        float v10 = sel0 ? p1.y : p1.x;
        float v11 = sel1 ? p1.x : p1.y;
        float v = v00 * w00 + v01 * w01 + v10 * w10 + v11 * w11;
        __builtin_nontemporal_store(v, ob + off);
    }
}

extern "C" void kernel_launch(void* const* d_in, const int* in_sizes, int n_in,
                              void* d_out, int out_size, void* d_ws, size_t ws_size,
                              hipStream_t stream) {
    const float* src  = (const float*)d_in[0];
    const float* flow = (const float*)d_in[1];
    float* out = (float*)d_out;
    dim3 grid(B_ * H_, 2);
    dim3 block(W_);
    st_warp_kernel<<<grid, block, 0, stream>>>(src, flow, out);
}

// Round 3
// 245.543 us; speedup vs baseline: 1.3215x; 1.1455x over previous
//
#include <hip/hip_runtime.h>

// Problem dims fixed by setup_inputs(): B=8, C=64, H=256, W=256.
#define B_ 8
#define C_ 64
#define H_ 256
#define W_ 256
#define RT 8       // output rows per block
#define CG 8       // channels per block
#define WIN 32     // staged src-row window (margin 12 above, 12 below -> |flow|<=11 safe)
#define PITCH 264  // LDS row pitch in floats: 16B-aligned rows, +8 bank skew per row

__global__ __launch_bounds__(256) void st_warp_kernel(
    const float* __restrict__ src,   // [B,C,H,W]
    const float* __restrict__ flow,  // [B,2,H,W]
    float* __restrict__ out)         // [B,C,H,W]
{
    __shared__ float tile[WIN * PITCH];   // 33,792 B

    const int HW = H_ * W_;

    // Grid: 2048 blocks = B * (H/RT) * (C/CG).
    // XCD swizzle: hardware round-robins id%8 across XCDs -> give each XCD one
    // batch. Within an XCD iterate row-tile fastest so concurrently-resident
    // blocks (~40/XCD) cover few channel-groups -> src working set ~4MB = L2.
    int id    = blockIdx.x;             // 0..2047
    int b     = id & 7;                 // batch -> XCD
    int local = id >> 3;                // 0..255
    int rt    = local & 31;             // row tile 0..31
    int cg    = local >> 5;             // channel group 0..7
    int r0    = rt * RT;
    int cbase = cg * CG;
    int w     = threadIdx.x;            // 0..255

    int ylo = r0 - 12;
    ylo = ylo < 0 ? 0 : (ylo > H_ - WIN ? H_ - WIN : ylo);

    // ---- Phase 1: per-pixel bilinear setup for 8 rows (registers) ----
    int   o0[RT], o1[RT];               // LDS word offsets of the two row-pairs
    float a00[RT], a01[RT], a10[RT], a11[RT];
    unsigned m0 = 0, m1 = 0;            // sel bitmasks (bit j)

    const float* flow_b = flow + (size_t)b * 2 * HW;

    #pragma unroll
    for (int j = 0; j < RT; ++j) {
        int h = r0 + j;
        float fy = flow_b[h * W_ + w];
        float fx = flow_b[HW + h * W_ + w];
        // replicate reference arithmetic incl. the identity round trip
        float new_y = (float)h + fy;
        float new_x = (float)w + fx;
        float ny = 2.0f * (new_y / (float)(H_ - 1) - 0.5f);
        float nx = 2.0f * (new_x / (float)(W_ - 1) - 0.5f);
        float py = (ny + 1.0f) * 0.5f * (float)(H_ - 1);
        float px = (nx + 1.0f) * 0.5f * (float)(W_ - 1);

        float y0f = floorf(py), x0f = floorf(px);
        int y0 = (int)y0f, x0 = (int)x0f;
        int y1 = y0 + 1,  x1 = x0 + 1;
        float wy1 = py - y0f, wy0 = 1.0f - wy1;
        float wx1 = px - x0f, wx0 = 1.0f - wx1;

        bool vy0 = (y0 >= 0) & (y0 < H_);
        bool vy1 = (y1 >= 0) & (y1 < H_);
        bool vx0 = (x0 >= 0) & (x0 < W_);
        bool vx1 = (x1 >= 0) & (x1 < W_);

        a00[j] = wy0 * wx0 * (float)(vy0 & vx0);
        a01[j] = wy0 * wx1 * (float)(vy0 & vx1);
        a10[j] = wy1 * wx0 * (float)(vy1 & vx0);
        a11[j] = wy1 * wx1 * (float)(vy1 & vx1);

        int y0c = min(max(y0, 0), H_ - 1);
        int y1c = min(max(y1, 0), H_ - 1);
        int x0c = min(max(x0, 0), W_ - 1);
        int x1c = min(max(x1, 0), W_ - 1);

        // pair trick: one 2-float window [xl, xl+1] covers both x taps
        int xl = min(max(x0, 0), W_ - 2);
        if (x0c != xl) m0 |= (1u << j);   // v00/v10 take .y
        if (x1c == xl) m1 |= (1u << j);   // v01/v11 take .x

        int rl0 = min(max(y0c - ylo, 0), WIN - 1);   // clamp: LDS-OOB safety
        int rl1 = min(max(y1c - ylo, 0), WIN - 1);
        o0[j] = rl0 * PITCH + xl;
        o1[j] = rl1 * PITCH + xl;
    }

    // ---- Phase 2: per channel: coalesced stage -> LDS gather -> store ----
    int rowblk = threadIdx.x >> 6;        // 0..3 (wave-uniform)
    int col    = (threadIdx.x & 63) * 4;  // 0..252

    size_t chan_stride = (size_t)HW;
    const float* sc0 = src + ((size_t)(b * C_ + cbase)) * chan_stride + (size_t)ylo * W_;
    float*       oc0 = out + ((size_t)(b * C_ + cbase)) * chan_stride + (size_t)r0 * W_ + w;

    for (int c = 0; c < CG; ++c) {
        const float* sc = sc0 + (size_t)c * chan_stride;
        float*       oc = oc0 + (size_t)c * chan_stride;

        // stage WIN rows, fully coalesced dwordx4 (1 KiB per wave-instr)
        #pragma unroll
        for (int it = 0; it < WIN / 4; ++it) {
            int r = it * 4 + rowblk;
            float4 v = *(const float4*)(sc + r * W_ + col);
            *(float4*)&tile[r * PITCH + col] = v;
        }
        __syncthreads();

        #pragma unroll
        for (int j = 0; j < RT; ++j) {
            float p0x = tile[o0[j]], p0y = tile[o0[j] + 1];
            float p1x = tile[o1[j]], p1y = tile[o1[j] + 1];
            float q00 = (m0 >> j) & 1 ? p0y : p0x;
            float q01 = (m1 >> j) & 1 ? p0x : p0y;
            float q10 = (m0 >> j) & 1 ? p1y : p1x;
            float q11 = (m1 >> j) & 1 ? p1x : p1y;
            float v = q00 * a00[j] + q01 * a01[j] + q10 * a10[j] + q11 * a11[j];
            __builtin_nontemporal_store(v, oc + j * W_);
        }
        __syncthreads();   // before next channel overwrites the tile
    }
}

extern "C" void kernel_launch(void* const* d_in, const int* in_sizes, int n_in,
                              void* d_out, int out_size, void* d_ws, size_t ws_size,
                              hipStream_t stream) {
    const float* src  = (const float*)d_in[0];
    const float* flow = (const float*)d_in[1];
    float* out = (float*)d_out;
    dim3 grid(B_ * (H_ / RT) * (C_ / CG));   // 2048
    dim3 block(256);
    st_warp_kernel<<<grid, block, 0, stream>>>(src, flow, out);
}